// Round 1
// baseline (153.367 us; speedup 1.0000x reference)
//
#include <hip/hip_runtime.h>

// Problem: O[b,q,e] = sum_k (Q[b,q,:]·K[b,k,:]) / (sqrt(D)*qk_sf) * V[b,k,e]
// No softmax -> associativity: O = Q @ (K^T @ V) * inv_scale.
// B=8, Sq=Sk=2048, D=Dv=128, fp32.

#define BATCH 8
#define SQ 2048
#define SK 2048
#define DIM 128

// ---------------- Kernel 1: T[b] = K[b]^T @ V[b]  (atomic accumulate) -------
// grid = BATCH * 32 (chunks of 64 k-rows), block = 256
__global__ __launch_bounds__(256) void ktv_kernel(const float* __restrict__ K,
                                                  const float* __restrict__ V,
                                                  float* __restrict__ T) {
    __shared__ float Kc[64 * DIM];
    __shared__ float Vc[64 * DIM];
    const int b = blockIdx.x >> 5;      // 32 chunks per batch
    const int k0 = (blockIdx.x & 31) * 64;
    const int tid = threadIdx.x;

    const float* Kg = K + ((size_t)b * SK + k0) * DIM;
    const float* Vg = V + ((size_t)b * SK + k0) * DIM;

    // 64*128 floats = 2048 float4; 256 threads * 8 each, coalesced
    #pragma unroll
    for (int i = 0; i < 8; i++) {
        int idx = tid + i * 256;
        ((float4*)Kc)[idx] = ((const float4*)Kg)[idx];
        ((float4*)Vc)[idx] = ((const float4*)Vg)[idx];
    }
    __syncthreads();

    const int td = tid >> 4;   // 0..15 : d-group
    const int te = tid & 15;   // 0..15 : e-group
    // thread owns d in {td*4..+3} U {64+td*4..+3}, e likewise (split layout
    // keeps float4 LDS reads at <=2 distinct words per bank -> conflict-free)

    float acc[8][8];
    #pragma unroll
    for (int i = 0; i < 8; i++)
        #pragma unroll
        for (int j = 0; j < 8; j++) acc[i][j] = 0.0f;

    for (int k = 0; k < 64; k++) {
        const float4 ka = *(const float4*)&Kc[k * DIM + td * 4];
        const float4 kb = *(const float4*)&Kc[k * DIM + 64 + td * 4];
        const float4 va = *(const float4*)&Vc[k * DIM + te * 4];
        const float4 vb = *(const float4*)&Vc[k * DIM + 64 + te * 4];
        const float kv[8] = {ka.x, ka.y, ka.z, ka.w, kb.x, kb.y, kb.z, kb.w};
        const float vv[8] = {va.x, va.y, va.z, va.w, vb.x, vb.y, vb.z, vb.w};
        #pragma unroll
        for (int i = 0; i < 8; i++)
            #pragma unroll
            for (int j = 0; j < 8; j++)
                acc[i][j] = fmaf(kv[i], vv[j], acc[i][j]);
    }

    float* Tb = T + (size_t)b * DIM * DIM;
    #pragma unroll
    for (int i = 0; i < 8; i++) {
        const int d = (i < 4) ? (td * 4 + i) : (64 + td * 4 + (i - 4));
        #pragma unroll
        for (int j = 0; j < 8; j++) {
            const int e = (j < 4) ? (te * 4 + j) : (64 + te * 4 + (j - 4));
            unsafeAtomicAdd(&Tb[d * DIM + e], acc[i][j]);
        }
    }
}

// ---------------- Kernel 2: O[b] = Q[b] @ T[b] * inv_scale ------------------
// grid = BATCH * 32 (chunks of 64 q-rows), block = 256
__global__ __launch_bounds__(256) void qt_kernel(const float* __restrict__ Q,
                                                 const float* __restrict__ T,
                                                 const float* __restrict__ qk_sf,
                                                 float* __restrict__ O) {
    __shared__ float Ts[DIM * DIM];     // 64 KB
    __shared__ float Qs[64 * 132];      // padded stride 132 breaks bank collision
    const int b = blockIdx.x >> 5;
    const int r0 = (blockIdx.x & 31) * 64;
    const int tid = threadIdx.x;

    const float* Tb = T + (size_t)b * DIM * DIM;
    #pragma unroll
    for (int i = 0; i < 16; i++) {      // 16384 floats = 4096 float4
        int idx = tid + i * 256;
        ((float4*)Ts)[idx] = ((const float4*)Tb)[idx];
    }
    const float* Qg = Q + ((size_t)b * SQ + r0) * DIM;
    #pragma unroll
    for (int i = 0; i < 8; i++) {       // 64*128 floats = 2048 float4
        int idx = tid + i * 256;
        int row = idx >> 5;             // 32 float4 per source row
        int col = idx & 31;
        float4 v = ((const float4*)Qg)[idx];
        *(float4*)&Qs[row * 132 + col * 4] = v;
    }
    __syncthreads();

    const float s = 1.0f / (sqrtf(128.0f) * qk_sf[0]);
    const int eg = tid & 31;            // e-quad: e in eg*4..eg*4+3
    const int qg = tid >> 3 >> 2;       // 0..7 : q-rows qg*8..qg*8+7
    float4 acc[8];
    #pragma unroll
    for (int i = 0; i < 8; i++) acc[i] = make_float4(0.f, 0.f, 0.f, 0.f);

    for (int d = 0; d < DIM; d += 4) {
        float4 t[4];
        #pragma unroll
        for (int dd = 0; dd < 4; dd++)
            t[dd] = *(const float4*)&Ts[(d + dd) * DIM + eg * 4];
        #pragma unroll
        for (int i = 0; i < 8; i++) {
            const int q = qg * 8 + i;
            const float4 qv = *(const float4*)&Qs[q * 132 + d];
            const float qa[4] = {qv.x, qv.y, qv.z, qv.w};
            #pragma unroll
            for (int dd = 0; dd < 4; dd++) {
                acc[i].x = fmaf(qa[dd], t[dd].x, acc[i].x);
                acc[i].y = fmaf(qa[dd], t[dd].y, acc[i].y);
                acc[i].z = fmaf(qa[dd], t[dd].z, acc[i].z);
                acc[i].w = fmaf(qa[dd], t[dd].w, acc[i].w);
            }
        }
    }

    float* Og = O + ((size_t)b * SQ + r0) * DIM;
    #pragma unroll
    for (int i = 0; i < 8; i++) {
        const int q = qg * 8 + i;
        float4 o = acc[i];
        o.x *= s; o.y *= s; o.z *= s; o.w *= s;
        ((float4*)Og)[q * 32 + eg] = o;
    }
}

extern "C" void kernel_launch(void* const* d_in, const int* in_sizes, int n_in,
                              void* d_out, int out_size, void* d_ws, size_t ws_size,
                              hipStream_t stream) {
    // inputs: 0=qk (dummy), 1=qk_scaling_factor, 2=query, 3=key, 4=value
    const float* qk_sf = (const float*)d_in[1];
    const float* Q = (const float*)d_in[2];
    const float* K = (const float*)d_in[3];
    const float* V = (const float*)d_in[4];
    float* O = (float*)d_out;
    float* T = (float*)d_ws;   // BATCH*128*128 floats = 512 KB

    hipMemsetAsync(T, 0, (size_t)BATCH * DIM * DIM * sizeof(float), stream);
    ktv_kernel<<<dim3(BATCH * 32), dim3(256), 0, stream>>>(K, V, T);
    qt_kernel<<<dim3(BATCH * 32), dim3(256), 0, stream>>>(Q, T, qk_sf, O);
}

// Round 2
// 96.537 us; speedup vs baseline: 1.5887x; 1.5887x over previous
//
#include <hip/hip_runtime.h>

// O[b,q,e] = sum_k (Q·K)/ (sqrt(128)*qk_sf) * V  ==  Q @ (K^T V) * s   (no softmax)
// B=8, S=2048, D=128 fp32.
// K1: P'[blk][e=128][d=64] = partial V^T K (bf16, transposed so K2/K3 need no transpose)
// K2: Tt[b][e][d] = s * sum_chunks P'   (bf16, scale folded)
// K3: O = Q @ T via mfma_f32_16x16x32_bf16, B-frag reads Tt contiguously.

#define BATCH 8
#define SEQ 2048
#define DIM 128

typedef __attribute__((ext_vector_type(8))) short short8;
typedef __attribute__((ext_vector_type(4))) float f32x4;

__device__ __forceinline__ unsigned int f2bf(float f) {
    unsigned int u = __float_as_uint(f);
    u += 0x7fffu + ((u >> 16) & 1u);   // RNE
    return u >> 16;
}

// ---------------- K1: partial V^T K ----------------------------------------
// grid = 512: blockIdx = ((b*32 + kc)*2 + dh); 64 k-rows, d-half of 64
__global__ __launch_bounds__(256) void vtk_partial(const float* __restrict__ K,
                                                   const float* __restrict__ V,
                                                   unsigned short* __restrict__ P) {
    __shared__ float Vc[64 * 128];   // 32 KB
    __shared__ float Kc[64 * 64];    // 16 KB
    const int blk = blockIdx.x;
    const int b   = blk >> 6;
    const int kc  = (blk >> 1) & 31;
    const int dh  = blk & 1;
    const int tid = threadIdx.x;

    const float* Vg = V + ((size_t)b * SEQ + kc * 64) * DIM;
    const float* Kg = K + ((size_t)b * SEQ + kc * 64) * DIM + dh * 64;

    #pragma unroll
    for (int i = 0; i < 8; i++) {                 // 2048 float4
        int idx = tid + i * 256;
        ((float4*)Vc)[idx] = ((const float4*)Vg)[idx];
    }
    #pragma unroll
    for (int i = 0; i < 4; i++) {                 // 1024 float4 (64-col slice)
        int idx = tid + i * 256;
        int r = idx >> 4, c = idx & 15;
        ((float4*)Kc)[idx] = *(const float4*)(Kg + r * DIM + c * 4);
    }
    __syncthreads();

    const int td = tid & 15;    // d-group: 4 consecutive d
    const int te = tid >> 4;    // e-group: 8 consecutive e

    float acc[8][4];
    #pragma unroll
    for (int i = 0; i < 8; i++)
        #pragma unroll
        for (int j = 0; j < 4; j++) acc[i][j] = 0.0f;

    for (int k = 0; k < 64; k++) {
        const float4 kd = *(const float4*)&Kc[k * 64 + td * 4];
        const float4 va = *(const float4*)&Vc[k * 128 + te * 8];
        const float4 vb = *(const float4*)&Vc[k * 128 + te * 8 + 4];
        const float ve[8] = {va.x, va.y, va.z, va.w, vb.x, vb.y, vb.z, vb.w};
        const float kv[4] = {kd.x, kd.y, kd.z, kd.w};
        #pragma unroll
        for (int i = 0; i < 8; i++)
            #pragma unroll
            for (int j = 0; j < 4; j++)
                acc[i][j] = fmaf(ve[i], kv[j], acc[i][j]);
    }

    unsigned short* Pb = P + (size_t)blk * 8192;
    #pragma unroll
    for (int i = 0; i < 8; i++) {
        uint2 w;
        w.x = f2bf(acc[i][0]) | (f2bf(acc[i][1]) << 16);
        w.y = f2bf(acc[i][2]) | (f2bf(acc[i][3]) << 16);
        *(uint2*)(Pb + (te * 8 + i) * 64 + td * 4) = w;
    }
}

// ---------------- K2: reduce partials -> Tt[b][e][d] * s --------------------
// grid = 128 x 256 : one thread = 4 consecutive d for one (b,e)
__global__ __launch_bounds__(256) void reduce_t(const unsigned short* __restrict__ P,
                                                const float* __restrict__ qk_sf,
                                                unsigned short* __restrict__ Tt) {
    const int u   = blockIdx.x * 256 + threadIdx.x;  // 0..32767
    const int b   = u >> 12;
    const int rem = u & 4095;
    const int e   = rem >> 5;
    const int d0  = (rem & 31) * 4;
    const int dh  = d0 >> 6;
    const int dl  = d0 & 63;

    const unsigned short* Pb = P + ((size_t)(b * 64 + dh) * 8192) + e * 64 + dl;
    float a0 = 0.f, a1 = 0.f, a2 = 0.f, a3 = 0.f;
    #pragma unroll 8
    for (int kc = 0; kc < 32; kc++) {
        uint2 w = *(const uint2*)(Pb + (size_t)kc * 16384);
        a0 += __uint_as_float(w.x << 16);
        a1 += __uint_as_float(w.x & 0xffff0000u);
        a2 += __uint_as_float(w.y << 16);
        a3 += __uint_as_float(w.y & 0xffff0000u);
    }
    const float s = 1.0f / (sqrtf(128.0f) * qk_sf[0]);
    uint2 o;
    o.x = f2bf(a0 * s) | (f2bf(a1 * s) << 16);
    o.y = f2bf(a2 * s) | (f2bf(a3 * s) << 16);
    *(uint2*)(Tt + (size_t)b * 16384 + e * 128 + d0) = o;
}

// ---------------- K3: O = Q @ T  (MFMA bf16) --------------------------------
// grid = 512: blockIdx = b*64 + qc (32 q-rows per block)
__global__ __launch_bounds__(256) void qt_mfma(const float* __restrict__ Q,
                                               const unsigned short* __restrict__ Tt,
                                               float* __restrict__ O) {
    __shared__ unsigned short Ts[128 * 136];  // Tt[e][d], pad 136 (272 B row, 16B-aligned)
    __shared__ unsigned short Qs[32 * 136];   // Q[q][d] bf16
    const int b   = blockIdx.x >> 6;
    const int q0  = (blockIdx.x & 63) * 32;
    const int tid = threadIdx.x;

    const uint4* Tg = (const uint4*)(Tt + (size_t)b * 16384);  // 2048 uint4
    #pragma unroll
    for (int i = 0; i < 8; i++) {
        int idx = tid + i * 256;
        int row = idx >> 4, c = idx & 15;
        *(uint4*)&Ts[row * 136 + c * 8] = Tg[idx];
    }
    const float4* Qg = (const float4*)(Q + ((size_t)b * SEQ + q0) * DIM); // 1024 float4
    #pragma unroll
    for (int i = 0; i < 4; i++) {
        int idx = tid + i * 256;
        int row = idx >> 5, c = idx & 31;
        float4 v = Qg[idx];
        uint2 w;
        w.x = f2bf(v.x) | (f2bf(v.y) << 16);
        w.y = f2bf(v.z) | (f2bf(v.w) << 16);
        *(uint2*)&Qs[row * 136 + c * 4] = w;
    }
    __syncthreads();

    const int wave = tid >> 6, lane = tid & 63;
    const int lm   = lane & 15, quad = lane >> 4;
    const int mrow = (wave & 1) * 16;        // q-tile within block
    const int n0   = (wave >> 1) * 64;       // e-range (4 n-tiles of 16)

    f32x4 acc[4] = {{0,0,0,0},{0,0,0,0},{0,0,0,0},{0,0,0,0}};
    #pragma unroll
    for (int ks = 0; ks < 4; ks++) {         // K = 128 in steps of 32
        short8 a = *(const short8*)&Qs[(mrow + lm) * 136 + ks * 32 + quad * 8];
        #pragma unroll
        for (int nt = 0; nt < 4; nt++) {
            short8 bb = *(const short8*)&Ts[(n0 + nt * 16 + lm) * 136 + ks * 32 + quad * 8];
            acc[nt] = __builtin_amdgcn_mfma_f32_16x16x32_bf16(a, bb, acc[nt], 0, 0, 0);
        }
    }

    float* Og = O + ((size_t)b * SEQ + q0) * DIM;
    #pragma unroll
    for (int nt = 0; nt < 4; nt++)
        #pragma unroll
        for (int r = 0; r < 4; r++) {
            const int row = mrow + quad * 4 + r;        // C/D: row = quad*4 + reg
            const int col = n0 + nt * 16 + lm;          //      col = lane&15
            Og[row * DIM + col] = acc[nt][r];
        }
}

extern "C" void kernel_launch(void* const* d_in, const int* in_sizes, int n_in,
                              void* d_out, int out_size, void* d_ws, size_t ws_size,
                              hipStream_t stream) {
    const float* qk_sf = (const float*)d_in[1];
    const float* Q = (const float*)d_in[2];
    const float* K = (const float*)d_in[3];
    const float* V = (const float*)d_in[4];
    float* O = (float*)d_out;

    unsigned short* P  = (unsigned short*)d_ws;                       // 512*8192*2B = 8 MB
    unsigned short* Tt = (unsigned short*)((char*)d_ws + (size_t)512 * 8192 * 2);

    vtk_partial<<<dim3(512), dim3(256), 0, stream>>>(K, V, P);
    reduce_t<<<dim3(128), dim3(256), 0, stream>>>(P, qk_sf, Tt);
    qt_mfma<<<dim3(BATCH * 64), dim3(256), 0, stream>>>(Q, Tt, O);
}